// Round 12
// baseline (133.224 us; speedup 1.0000x reference)
//
#include <hip/hip_runtime.h>

// Problem constants (B=1)
constexpr int L  = 2048;
constexpr int D  = 1024;
constexpr int H  = 16;
constexpr int F  = 16;   // qk feature dim per head
constexpr int HD = 64;   // v head dim
constexpr int CHUNK = 128;
constexpr int NC = L / CHUNK;  // 16

typedef __bf16 bf16x8 __attribute__((ext_vector_type(8)));
typedef float  f32x16 __attribute__((ext_vector_type(16)));
typedef int    i32x4  __attribute__((ext_vector_type(4)));

__device__ __forceinline__ ushort f2bf(float f) {
  uint u = __builtin_bit_cast(uint, f);
  uint r = (u + 0x7FFFu + ((u >> 16) & 1u)) >> 16;
  return (ushort)r;
}
__device__ __forceinline__ float bf2f(ushort h) {
  uint u = ((uint)h) << 16;
  return __builtin_bit_cast(float, u);
}

// 5-slice signed-7-bit split of fp32 (scales 2^-4,2^-11,2^-18,2^-25,2^-32).
__device__ __forceinline__ void split5(float x, signed char s[5]) {
  float t = rintf(x * 16.f);              s[0] = (signed char)t;
  float r = fmaf(t, -6.25e-2f, x);
  t = rintf(r * 2048.f);                  s[1] = (signed char)t;
  r = fmaf(t, -4.8828125e-4f, r);
  t = rintf(r * 262144.f);                s[2] = (signed char)t;
  r = fmaf(t, -3.814697265625e-6f, r);
  t = rintf(r * 33554432.f);              s[3] = (signed char)t;
  r = fmaf(t, -2.9802322387695312e-8f, r);
  t = rintf(r * 4294967296.f);            s[4] = (signed char)t;
}

// ---------------------------------------------------------------------------
// Fused prep  [proven round 11 verbatim].
// blocks [0,2048): hs -> Ah bf16 + A8 int8x5.
// blocks [2048,5120): z=0 Wv->BvT, z=1 Wo->BoT, z=2 Wq|Wk->W8.
// ---------------------------------------------------------------------------
__global__ __launch_bounds__(256) void prep_all(
    const float* __restrict__ X,
    const float* __restrict__ Wv, const float* __restrict__ Wo,
    const float* __restrict__ Wq, const float* __restrict__ Wk,
    ushort* __restrict__ Ah, signed char* __restrict__ A8,
    ushort* __restrict__ BvT, ushort* __restrict__ BoT, signed char* __restrict__ W8) {
  __shared__ float t[32][33];
  const int tid = threadIdx.x;
  const int b = blockIdx.x;
  if (b < 2048) {
    const int plane = L * D;
    int idx = b * 256 + tid;
    float4 v = ((const float4*)X)[idx];
    ushort4 hh;
    hh.x = f2bf(v.x); hh.y = f2bf(v.y); hh.z = f2bf(v.z); hh.w = f2bf(v.w);
    ((ushort4*)Ah)[idx] = hh;
    signed char sx[5], sy[5], sz[5], sw[5];
    split5(v.x, sx); split5(v.y, sy); split5(v.z, sz); split5(v.w, sw);
    #pragma unroll
    for (int s = 0; s < 5; ++s) {
      char4 c; c.x = sx[s]; c.y = sy[s]; c.z = sz[s]; c.w = sw[s];
      ((char4*)(A8 + (size_t)s * plane))[idx] = c;
    }
    return;
  }
  const int bb = b - 2048;
  const int z = bb >> 10;
  const int bx = (bb & 1023) & 31, by = (bb & 1023) >> 5;
  const int lx = tid & 31, ly = tid >> 5;
  if (z == 2) {
    if (bx >= 16) return;
    const int plane = 512 * 1024;
    const int bn = bx * 32, bk = by * 32;
    const float* W = (bn < 256) ? Wq : Wk;
    const int wn = bn & 255;
    #pragma unroll
    for (int i = 0; i < 32; i += 8)
      t[ly + i][lx] = W[(size_t)(bk + ly + i) * 256 + wn + lx];
    __syncthreads();
    #pragma unroll
    for (int i = 0; i < 32; i += 8) {
      float v = t[lx][ly + i];
      signed char s[5];
      split5(v, s);
      size_t base = (size_t)(bn + ly + i) * 1024 + bk + lx;
      #pragma unroll
      for (int si = 0; si < 5; ++si) W8[(size_t)si * plane + base] = s[si];
    }
    return;
  }
  const float* W = z ? Wo : Wv;
  ushort* BT = z ? BoT : BvT;
  const int bn = bx * 32, bk = by * 32;
  #pragma unroll
  for (int i = 0; i < 32; i += 8)
    t[ly + i][lx] = W[(size_t)(bk + ly + i) * 1024 + bn + lx];
  __syncthreads();
  #pragma unroll
  for (int i = 0; i < 32; i += 8) {
    float v = t[lx][ly + i];
    BT[(size_t)(bn + ly + i) * 1024 + bk + lx] = f2bf(v);
  }
}

// ---------------------------------------------------------------------------
// Fused independent GEMMs  [proven round 11; V epilogue now writes bf16].
// blocks [0,256) = exact QK via i8 MFMA; blocks [256,512) = V projection.
// ---------------------------------------------------------------------------
__global__ __launch_bounds__(512) void gemm_v_qk(
    const signed char* __restrict__ A8, const signed char* __restrict__ W8,
    float* __restrict__ Qo, float* __restrict__ Ko,
    const ushort* __restrict__ Av, const ushort* __restrict__ BvT,
    ushort* __restrict__ Vb16) {
  __shared__ __align__(16) char lds_raw[51200];
  const int tid = threadIdx.x;
  const int bid = blockIdx.x;
  const int wave = tid >> 6, lane = tid & 63;

  if (bid < 256) {
    auto As = (signed char (*)[64][80])(lds_raw);
    auto Bs = (signed char (*)[64][80])(lds_raw + 25600);
    const int aplane = L * D;
    const int bplane = 512 * 1024;
    const int wm = (wave >> 2) * 32;
    const int wn = (wave & 3) * 16;
    int b2 = (bid & 7) * 32 + (bid >> 3);
    const int brow = (b2 >> 3) * 64, bcol = (b2 & 7) * 64;
    const int fr = lane & 15, kq = (lane >> 4) * 16;

    i32x4 acc[2][5];
    #pragma unroll
    for (int fm = 0; fm < 2; ++fm)
      #pragma unroll
      for (int g = 0; g < 5; ++g)
        #pragma unroll
        for (int r = 0; r < 4; ++r) acc[fm][g][r] = 0;

    for (int k0 = 0; k0 < D; k0 += 64) {
      #pragma unroll
      for (int i = 0; i < 5; ++i) {
        int c = i * 512 + tid;
        int side = (c >= 1280);
        int cc = side ? c - 1280 : c;
        int slice = cc >> 8, row = (cc & 255) >> 2, c16 = (cc & 3) * 16;
        const signed char* src = side
            ? &W8[(size_t)slice * bplane + (size_t)(bcol + row) * 1024 + k0 + c16]
            : &A8[(size_t)slice * aplane + (size_t)(brow + row) * 1024 + k0 + c16];
        int4 val = *(const int4*)src;
        signed char* dst = side ? &Bs[slice][row][c16] : &As[slice][row][c16];
        *(int4*)dst = val;
      }
      __syncthreads();
      i32x4 bfr[5], afr[2][5];
      #pragma unroll
      for (int s = 0; s < 5; ++s) bfr[s] = *(const i32x4*)&Bs[s][wn + fr][kq];
      #pragma unroll
      for (int fm = 0; fm < 2; ++fm)
        #pragma unroll
        for (int s = 0; s < 5; ++s)
          afr[fm][s] = *(const i32x4*)&As[s][wm + fm * 16 + fr][kq];
      #pragma unroll
      for (int fm = 0; fm < 2; ++fm) {
        acc[fm][0] = __builtin_amdgcn_mfma_i32_16x16x64_i8(afr[fm][0], bfr[0], acc[fm][0], 0, 0, 0);
        #pragma unroll
        for (int g = 1; g < 5; ++g)
          #pragma unroll
          for (int i = 0; i <= g; ++i)
            acc[fm][g] = __builtin_amdgcn_mfma_i32_16x16x64_i8(afr[fm][i], bfr[g - i], acc[fm][g], 0, 0, 0);
      }
      __syncthreads();
    }
    const double sc0 = 3.90625e-3, sc1 = 3.0517578125e-5, sc2 = 2.384185791015625e-7,
                 sc3 = 1.862645149230957e-9, sc4 = 1.4551915228366852e-11;
    float* Out = (bcol < 256) ? Qo : Ko;
    const int ocol = (bcol & 255) + wn + fr;
    #pragma unroll
    for (int fm = 0; fm < 2; ++fm)
      #pragma unroll
      for (int r = 0; r < 4; ++r) {
        double v = (double)acc[fm][0][r] * sc0 + (double)acc[fm][1][r] * sc1 +
                   (double)acc[fm][2][r] * sc2 + (double)acc[fm][3][r] * sc3 +
                   (double)acc[fm][4][r] * sc4;
        int row = brow + wm + fm * 16 + (lane >> 4) * 4 + r;
        Out[(size_t)row * 256 + ocol] = (float)v;
      }
    return;
  }

  // ---------------- V projection bf16, 128x64 tile, 8 waves, dbuf ---------
  auto AsV = (__bf16 (*)[128][40])(lds_raw);
  auto BsV = (__bf16 (*)[64][40])(lds_raw + 20480);
  const int vb0 = bid - 256;
  const int v2 = (vb0 & 7) * 32 + (vb0 >> 3);
  const int brow = (v2 >> 4) * 128, bcol = (v2 & 15) * 64;
  const int wm = (wave >> 1) * 32, wn = (wave & 1) * 32;
  const int srow = tid >> 2, skg = (tid & 3) * 8;
  const size_t a_off = (size_t)(brow + srow) * D + skg;
  const size_t b_off = (size_t)(bcol + (tid >> 2)) * D + skg;

  f32x16 acc;
  #pragma unroll
  for (int i = 0; i < 16; ++i) acc[i] = 0.f;

  bf16x8 ra, rb;
  auto LOADT = [&](int k0) {
    ra = *(const bf16x8*)&Av[a_off + k0];
    if (tid < 256) rb = *(const bf16x8*)&BvT[b_off + k0];
  };
  auto WRITET = [&](int buf) {
    *(bf16x8*)&AsV[buf][srow][skg] = ra;
    if (tid < 256) *(bf16x8*)&BsV[buf][tid >> 2][skg] = rb;
  };

  const int NS = D / 32;
  LOADT(0); WRITET(0);
  __syncthreads();
  int cur = 0;
  for (int t = 0; t < NS; ++t) {
    if (t + 1 < NS) LOADT((t + 1) * 32);
    const int fr = lane & 31;
    const int kh = (lane >> 5) * 8;
    bf16x8 a0 = *(const bf16x8*)&AsV[cur][wm + fr][kh];
    bf16x8 a1 = *(const bf16x8*)&AsV[cur][wm + fr][16 + kh];
    bf16x8 b0 = *(const bf16x8*)&BsV[cur][wn + fr][kh];
    bf16x8 b1 = *(const bf16x8*)&BsV[cur][wn + fr][16 + kh];
    acc = __builtin_amdgcn_mfma_f32_32x32x16_bf16(a0, b0, acc, 0, 0, 0);
    acc = __builtin_amdgcn_mfma_f32_32x32x16_bf16(a1, b1, acc, 0, 0, 0);
    if (t + 1 < NS) WRITET(cur ^ 1);
    __syncthreads();
    cur ^= 1;
  }
  const int fr = lane & 31, fq = lane >> 5;
  #pragma unroll
  for (int r = 0; r < 16; ++r) {
    int row = brow + wm + (r & 3) + 8 * (r >> 2) + 4 * fq;
    Vb16[(size_t)row * 1024 + bcol + wn + fr] = f2bf(acc[r]);
  }
}

// ---------------------------------------------------------------------------
// Fused chunk attention v5 = v4 main body [proven] + in-kernel inter-chunk
// state recompute (replaces chunk_state kernel): stream K/V chunks < c,
// accumulate Ss (fp32, 2 regs/thread) and kcs (fp64 lane partials + LDS
// reduce). V consumed as bf16. Flat grid 256, XCD-swizzled; 512 threads.
// ---------------------------------------------------------------------------
__global__ __launch_bounds__(512) void attn_chunk_v5(
    const float* __restrict__ Q, const float* __restrict__ Kq,
    const ushort* __restrict__ Vb16, ushort* __restrict__ Yh) {
  const int swz = (blockIdx.x & 7) * 32 + (blockIdx.x >> 3);
  const int h = swz >> 4, c = swz & 15;
  __shared__ float Ks[CHUNK][F];        // 8 KB   (chunk c K)
  __shared__ float Vs[CHUNK][HD];       // 32 KB  (chunk c V, f32)
  __shared__ float Kst[CHUNK][17];      // 8.5 KB (streamed K, padded)
  __shared__ ushort Vst[CHUNK][HD];     // 16 KB  (streamed V, bf16)
  __shared__ float Ssh[F][HD];          // 4 KB
  __shared__ double kred[F][32];        // 4 KB
  __shared__ double kcs[F];
  __shared__ float zs[CHUNK];
  const int tid = threadIdx.x;

  {  // Ks: 512 float4, 1/thread
    int m = tid >> 2, f0 = (tid & 3) * 4;
    *(float4*)&Ks[m][f0] = *(const float4*)&Kq[(size_t)(c * CHUNK + m) * (H * F) + h * F + f0];
  }
  #pragma unroll
  for (int i = 0; i < 2; ++i) {  // Vs: 1024 bf16x8 loads -> f32
    int g = i * 512 + tid;
    int m = g >> 3, e0 = (g & 7) * 8;
    bf16x8 vv = *(const bf16x8*)&Vb16[(size_t)(c * CHUNK + m) * 1024 + h * HD + e0];
    #pragma unroll
    for (int j = 0; j < 8; ++j) Vs[m][e0 + j] = bf2f(((ushort*)&vv)[j]);
  }

  // ---- inter-chunk state recompute (chunks 0..c-1) ----
  const int fS = tid >> 6;       // 0..7  (owns f=fS and f=fS+8)
  const int eS = tid & 63;
  const int fK = tid >> 5;       // 0..15 (kcs partials)
  const int mK = tid & 31;
  float s0 = 0.f, s1 = 0.f;
  double kcp = 0.0;
  for (int cc = 0; cc < c; ++cc) {
    __syncthreads();   // protect Kst/Vst from previous iteration's readers
    {  // stage K chunk cc (scalar stores: LD=17 breaks float4 alignment)
      int m = tid >> 2, f0 = (tid & 3) * 4;
      float4 kv = *(const float4*)&Kq[(size_t)(cc * CHUNK + m) * (H * F) + h * F + f0];
      Kst[m][f0 + 0] = kv.x; Kst[m][f0 + 1] = kv.y;
      Kst[m][f0 + 2] = kv.z; Kst[m][f0 + 3] = kv.w;
    }
    #pragma unroll
    for (int i = 0; i < 2; ++i) {  // stage V chunk cc (bf16 passthrough)
      int g = i * 512 + tid;
      int m = g >> 3, e0 = (g & 7) * 8;
      *(bf16x8*)&Vst[m][e0] =
          *(const bf16x8*)&Vb16[(size_t)(cc * CHUNK + m) * 1024 + h * HD + e0];
    }
    __syncthreads();
    for (int m = 0; m < CHUNK; ++m) {
      float kA = Kst[m][fS];
      float kB = Kst[m][fS + 8];
      float v = bf2f(Vst[m][eS]);
      s0 = fmaf(kA, v, s0);
      s1 = fmaf(kB, v, s1);
    }
    #pragma unroll
    for (int mm = 0; mm < 4; ++mm)
      kcp += (double)Kst[mm * 32 + mK][fK];
  }
  kred[fK][mK] = kcp;
  Ssh[fS][eS] = s0;
  Ssh[fS + 8][eS] = s1;
  __syncthreads();
  if (tid < F) {
    double s = 0.0;
    #pragma unroll
    for (int j = 0; j < 32; ++j) s += kred[tid][j];
    kcs[tid] = s;
  }
  __syncthreads();

  // ---- main intra-chunk loop (v4 proven body) ----
  const int w = tid >> 6;
  const int lane = tid & 63;
  const int rsub = lane >> 3;
  const int cg = lane & 7;
  const int e0 = cg * 8;
  const int lr = 8 * w + rsub;
  const int hr = 120 - 8 * w + rsub;

  float ql[F], qh[F];
  #pragma unroll
  for (int f0 = 0; f0 < F; f0 += 4) {
    *(float4*)&ql[f0] = *(const float4*)&Q[(size_t)(c * CHUNK + lr) * (H * F) + h * F + f0];
    *(float4*)&qh[f0] = *(const float4*)&Q[(size_t)(c * CHUNK + hr) * (H * F) + h * F + f0];
  }

  float accl[8], acch[8];
  #pragma unroll
  for (int j = 0; j < 8; ++j) { accl[j] = 0.f; acch[j] = 0.f; }
  float denl = 0.f, denh = 0.f;

  const int m1 = 8 * w + 8;
  const int m2 = 128 - 8 * w;
  for (int m = 0; m < m2; ++m) {
    float kr[F];
    #pragma unroll
    for (int f0 = 0; f0 < F; f0 += 4)
      *(float4*)&kr[f0] = *(const float4*)&Ks[m][f0];
    float v8[8];
    *(float4*)&v8[0] = *(const float4*)&Vs[m][e0];
    *(float4*)&v8[4] = *(const float4*)&Vs[m][e0 + 4];
    {
      float s = 0.f;
      #pragma unroll
      for (int f = 0; f < F; ++f) s = fmaf(qh[f], kr[f], s);
      float a = (m <= hr) ? s : 0.f;
      denh += a;
      #pragma unroll
      for (int j = 0; j < 8; ++j) acch[j] = fmaf(a, v8[j], acch[j]);
    }
    if (m < m1) {
      float s = 0.f;
      #pragma unroll
      for (int f = 0; f < F; ++f) s = fmaf(ql[f], kr[f], s);
      float a = (m <= lr) ? s : 0.f;
      denl += a;
      #pragma unroll
      for (int j = 0; j < 8; ++j) accl[j] = fmaf(a, v8[j], accl[j]);
    }
  }

  #pragma unroll
  for (int f = 0; f < F; ++f) {
    float s8[8];
    *(float4*)&s8[0] = *(const float4*)&Ssh[f][e0];
    *(float4*)&s8[4] = *(const float4*)&Ssh[f][e0 + 4];
    #pragma unroll
    for (int j = 0; j < 8; ++j) {
      accl[j] = fmaf(ql[f], s8[j], accl[j]);
      acch[j] = fmaf(qh[f], s8[j], acch[j]);
    }
  }

  if (cg == 0) {
    double dl = (double)denl, dh = (double)denh;
    #pragma unroll
    for (int f = 0; f < F; ++f) {
      dl += (double)ql[f] * kcs[f];
      dh += (double)qh[f] * kcs[f];
    }
    zs[lr] = (float)(1.0 / (dl + 1e-12));
    zs[hr] = (float)(1.0 / (dh + 1e-12));
  }
  __syncthreads();

  #pragma unroll
  for (int rr = 0; rr < 2; ++rr) {
    const int row = rr ? hr : lr;
    const float* ac = rr ? acch : accl;
    float zz = zs[row];
    ushort4 h4a, h4b;
    h4a.x = f2bf(ac[0] * zz); h4a.y = f2bf(ac[1] * zz);
    h4a.z = f2bf(ac[2] * zz); h4a.w = f2bf(ac[3] * zz);
    h4b.x = f2bf(ac[4] * zz); h4b.y = f2bf(ac[5] * zz);
    h4b.z = f2bf(ac[6] * zz); h4b.w = f2bf(ac[7] * zz);
    size_t base = (size_t)(c * CHUNK + row) * 1024 + h * HD + e0;
    *(ushort4*)&Yh[base]     = h4a;
    *(ushort4*)&Yh[base + 4] = h4b;
  }
}

// ---------------------------------------------------------------------------
// Plain bf16 single-product GEMM  [proven round 10] (Wo projection).
// ---------------------------------------------------------------------------
__global__ __launch_bounds__(256) void gemm_bf16_db(
    const ushort* __restrict__ A, const ushort* __restrict__ BT,
    float* __restrict__ C, int M, int N, int K) {
  constexpr int LDT = 40;
  __shared__ __bf16 As[2][64][LDT];
  __shared__ __bf16 Bs[2][64][LDT];
  const int tid  = threadIdx.x;
  const int wave = tid >> 6, lane = tid & 63;
  const int wr = (wave >> 1) * 32, wc = (wave & 1) * 32;
  const int nbx = gridDim.x, nwg = gridDim.x * gridDim.y;
  int bid = blockIdx.y * nbx + blockIdx.x;
  bid = (bid & 7) * (nwg >> 3) + (bid >> 3);
  const int brow = (bid / nbx) * 64, bcol = (bid % nbx) * 64;
  const int srow = tid >> 2, skg = (tid & 3) * 8;
  const size_t a_off = (size_t)(brow + srow) * K + skg;
  const size_t b_off = (size_t)(bcol + srow) * K + skg;

  f32x16 acc;
  #pragma unroll
  for (int i = 0; i < 16; ++i) acc[i] = 0.f;

  bf16x8 ra, rb;
  auto LOADT = [&](int k0) {
    ra = *(const bf16x8*)&A[a_off + k0];
    rb = *(const bf16x8*)&BT[b_off + k0];
  };
  auto WRITET = [&](int buf) {
    *(bf16x8*)&As[buf][srow][skg] = ra;
    *(bf16x8*)&Bs[buf][srow][skg] = rb;
  };

  const int NS = K / 32;
  LOADT(0); WRITET(0);
  __syncthreads();
  int cur = 0;
  for (int t = 0; t < NS; ++t) {
    if (t + 1 < NS) LOADT((t + 1) * 32);
    const int fr = lane & 31;
    const int kh = (lane >> 5) * 8;
    bf16x8 a0 = *(const bf16x8*)&As[cur][wr + fr][kh];
    bf16x8 a1 = *(const bf16x8*)&As[cur][wr + fr][16 + kh];
    bf16x8 b0 = *(const bf16x8*)&Bs[cur][wc + fr][kh];
    bf16x8 b1 = *(const bf16x8*)&Bs[cur][wc + fr][16 + kh];
    acc = __builtin_amdgcn_mfma_f32_32x32x16_bf16(a0, b0, acc, 0, 0, 0);
    acc = __builtin_amdgcn_mfma_f32_32x32x16_bf16(a1, b1, acc, 0, 0, 0);
    if (t + 1 < NS) WRITET(cur ^ 1);
    __syncthreads();
    cur ^= 1;
  }
  const int fr = lane & 31, fq = lane >> 5;
  #pragma unroll
  for (int r = 0; r < 16; ++r) {
    int row = brow + wr + (r & 3) + 8 * (r >> 2) + 4 * fq;
    C[(size_t)row * N + bcol + wc + fr] = acc[r];
  }
}

// ---------------------------------------------------------------------------
extern "C" void kernel_launch(void* const* d_in, const int* in_sizes, int n_in,
                              void* d_out, int out_size, void* d_ws, size_t ws_size,
                              hipStream_t stream) {
  const float* hs = (const float*)d_in[0];
  const float* Wq = (const float*)d_in[1];
  const float* Wk = (const float*)d_in[2];
  const float* Wv = (const float*)d_in[3];
  const float* Wo = (const float*)d_in[4];
  float* out = (float*)d_out;

  char* ws = (char*)d_ws;
  const size_t MB = 1 << 20;
  signed char* A8 = (signed char*)(ws + 0 * MB);   // 10 MB, dead after step 2
  signed char* W8 = (signed char*)(ws + 10 * MB);  // 2.5 MB, dead after step 2
  ushort* Ah   = (ushort*)(ws + 13 * MB);          // 4 MB, dead after step 2
  ushort* BvT  = (ushort*)(ws + 17 * MB);          // 2 MB
  ushort* BoT  = (ushort*)(ws + 19 * MB);          // 2 MB
  ushort* Vb16 = (ushort*)(ws + 21 * MB);          // 4 MB bf16
  float*  Qb   = (float*)(ws + 25 * MB);           // 2 MB
  ushort* Ys   = (ushort*)(ws + 0 * MB);           // 4 MB bf16, overlays dead A8
  // d_out as scratch (proven): fully overwritten by step 4.
  float*  Kb   = (float*)((char*)d_out + 1 * MB);  // 2 MB

  // 1) fused prep: Ah + A8 from hs; BvT, BoT, W8 from weights
  prep_all<<<dim3(5120), 256, 0, stream>>>(hs, Wv, Wo, Wq, Wk, Ah, A8, BvT, BoT, W8);
  // 2) fused independent GEMMs: exact QK (i8) + V projection (bf16 out)
  gemm_v_qk<<<dim3(512), 512, 0, stream>>>(A8, W8, Qb, Kb, Ah, BvT, Vb16);
  // 3) fused attention v5 (in-kernel state recompute) -> Ys bf16
  attn_chunk_v5<<<dim3(256), 512, 0, stream>>>(Qb, Kb, Vb16, Ys);
  // 4) output projection (overwrites d_out, retiring Kb scratch)
  gemm_bf16_db<<<dim3(16, 32), 256, 0, stream>>>(Ys, BoT, out, L, D, H * HD);
}

// Round 13
// 90.735 us; speedup vs baseline: 1.4683x; 1.4683x over previous
//
#include <hip/hip_runtime.h>

// Problem constants (B=1)
constexpr int L  = 2048;
constexpr int D  = 1024;
constexpr int H  = 16;
constexpr int F  = 16;   // qk feature dim per head
constexpr int HD = 64;   // v head dim
constexpr int CHUNK = 128;
constexpr int NC = L / CHUNK;  // 16

typedef __bf16 bf16x8 __attribute__((ext_vector_type(8)));
typedef float  f32x16 __attribute__((ext_vector_type(16)));
typedef int    i32x4  __attribute__((ext_vector_type(4)));

__device__ __forceinline__ ushort f2bf(float f) {
  uint u = __builtin_bit_cast(uint, f);
  uint r = (u + 0x7FFFu + ((u >> 16) & 1u)) >> 16;
  return (ushort)r;
}
__device__ __forceinline__ float bf2f(ushort h) {
  uint u = ((uint)h) << 16;
  return __builtin_bit_cast(float, u);
}

// 5-slice signed-7-bit split of fp32 (scales 2^-4,2^-11,2^-18,2^-25,2^-32).
__device__ __forceinline__ void split5(float x, signed char s[5]) {
  float t = rintf(x * 16.f);              s[0] = (signed char)t;
  float r = fmaf(t, -6.25e-2f, x);
  t = rintf(r * 2048.f);                  s[1] = (signed char)t;
  r = fmaf(t, -4.8828125e-4f, r);
  t = rintf(r * 262144.f);                s[2] = (signed char)t;
  r = fmaf(t, -3.814697265625e-6f, r);
  t = rintf(r * 33554432.f);              s[3] = (signed char)t;
  r = fmaf(t, -2.9802322387695312e-8f, r);
  t = rintf(r * 4294967296.f);            s[4] = (signed char)t;
}

// ---------------------------------------------------------------------------
// Fused prep  [proven round 11 verbatim].
// ---------------------------------------------------------------------------
__global__ __launch_bounds__(256) void prep_all(
    const float* __restrict__ X,
    const float* __restrict__ Wv, const float* __restrict__ Wo,
    const float* __restrict__ Wq, const float* __restrict__ Wk,
    ushort* __restrict__ Ah, signed char* __restrict__ A8,
    ushort* __restrict__ BvT, ushort* __restrict__ BoT, signed char* __restrict__ W8) {
  __shared__ float t[32][33];
  const int tid = threadIdx.x;
  const int b = blockIdx.x;
  if (b < 2048) {
    const int plane = L * D;
    int idx = b * 256 + tid;
    float4 v = ((const float4*)X)[idx];
    ushort4 hh;
    hh.x = f2bf(v.x); hh.y = f2bf(v.y); hh.z = f2bf(v.z); hh.w = f2bf(v.w);
    ((ushort4*)Ah)[idx] = hh;
    signed char sx[5], sy[5], sz[5], sw[5];
    split5(v.x, sx); split5(v.y, sy); split5(v.z, sz); split5(v.w, sw);
    #pragma unroll
    for (int s = 0; s < 5; ++s) {
      char4 c; c.x = sx[s]; c.y = sy[s]; c.z = sz[s]; c.w = sw[s];
      ((char4*)(A8 + (size_t)s * plane))[idx] = c;
    }
    return;
  }
  const int bb = b - 2048;
  const int z = bb >> 10;
  const int bx = (bb & 1023) & 31, by = (bb & 1023) >> 5;
  const int lx = tid & 31, ly = tid >> 5;
  if (z == 2) {
    if (bx >= 16) return;
    const int plane = 512 * 1024;
    const int bn = bx * 32, bk = by * 32;
    const float* W = (bn < 256) ? Wq : Wk;
    const int wn = bn & 255;
    #pragma unroll
    for (int i = 0; i < 32; i += 8)
      t[ly + i][lx] = W[(size_t)(bk + ly + i) * 256 + wn + lx];
    __syncthreads();
    #pragma unroll
    for (int i = 0; i < 32; i += 8) {
      float v = t[lx][ly + i];
      signed char s[5];
      split5(v, s);
      size_t base = (size_t)(bn + ly + i) * 1024 + bk + lx;
      #pragma unroll
      for (int si = 0; si < 5; ++si) W8[(size_t)si * plane + base] = s[si];
    }
    return;
  }
  const float* W = z ? Wo : Wv;
  ushort* BT = z ? BoT : BvT;
  const int bn = bx * 32, bk = by * 32;
  #pragma unroll
  for (int i = 0; i < 32; i += 8)
    t[ly + i][lx] = W[(size_t)(bk + ly + i) * 1024 + bn + lx];
  __syncthreads();
  #pragma unroll
  for (int i = 0; i < 32; i += 8) {
    float v = t[lx][ly + i];
    BT[(size_t)(bn + ly + i) * 1024 + bk + lx] = f2bf(v);
  }
}

// ---------------------------------------------------------------------------
// Fused independent GEMMs  [proven rounds 11/12]. V epilogue writes bf16
// (validated round 12: absmax unchanged).
// ---------------------------------------------------------------------------
__global__ __launch_bounds__(512) void gemm_v_qk(
    const signed char* __restrict__ A8, const signed char* __restrict__ W8,
    float* __restrict__ Qo, float* __restrict__ Ko,
    const ushort* __restrict__ Av, const ushort* __restrict__ BvT,
    ushort* __restrict__ Vb16) {
  __shared__ __align__(16) char lds_raw[51200];
  const int tid = threadIdx.x;
  const int bid = blockIdx.x;
  const int wave = tid >> 6, lane = tid & 63;

  if (bid < 256) {
    auto As = (signed char (*)[64][80])(lds_raw);
    auto Bs = (signed char (*)[64][80])(lds_raw + 25600);
    const int aplane = L * D;
    const int bplane = 512 * 1024;
    const int wm = (wave >> 2) * 32;
    const int wn = (wave & 3) * 16;
    int b2 = (bid & 7) * 32 + (bid >> 3);
    const int brow = (b2 >> 3) * 64, bcol = (b2 & 7) * 64;
    const int fr = lane & 15, kq = (lane >> 4) * 16;

    i32x4 acc[2][5];
    #pragma unroll
    for (int fm = 0; fm < 2; ++fm)
      #pragma unroll
      for (int g = 0; g < 5; ++g)
        #pragma unroll
        for (int r = 0; r < 4; ++r) acc[fm][g][r] = 0;

    for (int k0 = 0; k0 < D; k0 += 64) {
      #pragma unroll
      for (int i = 0; i < 5; ++i) {
        int c = i * 512 + tid;
        int side = (c >= 1280);
        int cc = side ? c - 1280 : c;
        int slice = cc >> 8, row = (cc & 255) >> 2, c16 = (cc & 3) * 16;
        const signed char* src = side
            ? &W8[(size_t)slice * bplane + (size_t)(bcol + row) * 1024 + k0 + c16]
            : &A8[(size_t)slice * aplane + (size_t)(brow + row) * 1024 + k0 + c16];
        int4 val = *(const int4*)src;
        signed char* dst = side ? &Bs[slice][row][c16] : &As[slice][row][c16];
        *(int4*)dst = val;
      }
      __syncthreads();
      i32x4 bfr[5], afr[2][5];
      #pragma unroll
      for (int s = 0; s < 5; ++s) bfr[s] = *(const i32x4*)&Bs[s][wn + fr][kq];
      #pragma unroll
      for (int fm = 0; fm < 2; ++fm)
        #pragma unroll
        for (int s = 0; s < 5; ++s)
          afr[fm][s] = *(const i32x4*)&As[s][wm + fm * 16 + fr][kq];
      #pragma unroll
      for (int fm = 0; fm < 2; ++fm) {
        acc[fm][0] = __builtin_amdgcn_mfma_i32_16x16x64_i8(afr[fm][0], bfr[0], acc[fm][0], 0, 0, 0);
        #pragma unroll
        for (int g = 1; g < 5; ++g)
          #pragma unroll
          for (int i = 0; i <= g; ++i)
            acc[fm][g] = __builtin_amdgcn_mfma_i32_16x16x64_i8(afr[fm][i], bfr[g - i], acc[fm][g], 0, 0, 0);
      }
      __syncthreads();
    }
    const double sc0 = 3.90625e-3, sc1 = 3.0517578125e-5, sc2 = 2.384185791015625e-7,
                 sc3 = 1.862645149230957e-9, sc4 = 1.4551915228366852e-11;
    float* Out = (bcol < 256) ? Qo : Ko;
    const int ocol = (bcol & 255) + wn + fr;
    #pragma unroll
    for (int fm = 0; fm < 2; ++fm)
      #pragma unroll
      for (int r = 0; r < 4; ++r) {
        double v = (double)acc[fm][0][r] * sc0 + (double)acc[fm][1][r] * sc1 +
                   (double)acc[fm][2][r] * sc2 + (double)acc[fm][3][r] * sc3 +
                   (double)acc[fm][4][r] * sc4;
        int row = brow + wm + fm * 16 + (lane >> 4) * 4 + r;
        Out[(size_t)row * 256 + ocol] = (float)v;
      }
    return;
  }

  // ---------------- V projection bf16, 128x64 tile, 8 waves, dbuf ---------
  auto AsV = (__bf16 (*)[128][40])(lds_raw);
  auto BsV = (__bf16 (*)[64][40])(lds_raw + 20480);
  const int vb0 = bid - 256;
  const int v2 = (vb0 & 7) * 32 + (vb0 >> 3);
  const int brow = (v2 >> 4) * 128, bcol = (v2 & 15) * 64;
  const int wm = (wave >> 1) * 32, wn = (wave & 1) * 32;
  const int srow = tid >> 2, skg = (tid & 3) * 8;
  const size_t a_off = (size_t)(brow + srow) * D + skg;
  const size_t b_off = (size_t)(bcol + (tid >> 2)) * D + skg;

  f32x16 acc;
  #pragma unroll
  for (int i = 0; i < 16; ++i) acc[i] = 0.f;

  bf16x8 ra, rb;
  auto LOADT = [&](int k0) {
    ra = *(const bf16x8*)&Av[a_off + k0];
    if (tid < 256) rb = *(const bf16x8*)&BvT[b_off + k0];
  };
  auto WRITET = [&](int buf) {
    *(bf16x8*)&AsV[buf][srow][skg] = ra;
    if (tid < 256) *(bf16x8*)&BsV[buf][tid >> 2][skg] = rb;
  };

  const int NS = D / 32;
  LOADT(0); WRITET(0);
  __syncthreads();
  int cur = 0;
  for (int t = 0; t < NS; ++t) {
    if (t + 1 < NS) LOADT((t + 1) * 32);
    const int fr = lane & 31;
    const int kh = (lane >> 5) * 8;
    bf16x8 a0 = *(const bf16x8*)&AsV[cur][wm + fr][kh];
    bf16x8 a1 = *(const bf16x8*)&AsV[cur][wm + fr][16 + kh];
    bf16x8 b0 = *(const bf16x8*)&BsV[cur][wn + fr][kh];
    bf16x8 b1 = *(const bf16x8*)&BsV[cur][wn + fr][16 + kh];
    acc = __builtin_amdgcn_mfma_f32_32x32x16_bf16(a0, b0, acc, 0, 0, 0);
    acc = __builtin_amdgcn_mfma_f32_32x32x16_bf16(a1, b1, acc, 0, 0, 0);
    if (t + 1 < NS) WRITET(cur ^ 1);
    __syncthreads();
    cur ^= 1;
  }
  const int fr = lane & 31, fq = lane >> 5;
  #pragma unroll
  for (int r = 0; r < 16; ++r) {
    int row = brow + wm + (r & 3) + 8 * (r >> 2) + 4 * fq;
    Vb16[(size_t)row * 1024 + bcol + wn + fr] = f2bf(acc[r]);
  }
}

// ---------------------------------------------------------------------------
// Per-chunk state sums  [proven body; V now consumed as bf16].
// Grid (NC, H), 256 threads.
// ---------------------------------------------------------------------------
__global__ __launch_bounds__(256) void chunk_state(
    const float* __restrict__ Kq, const ushort* __restrict__ Vb16,
    float* __restrict__ S, double* __restrict__ KS) {
  const int c = blockIdx.x, h = blockIdx.y;
  __shared__ float Ks[CHUNK][F];
  __shared__ float Vs[CHUNK][HD];
  const int tid = threadIdx.x;
  #pragma unroll
  for (int i = 0; i < 2; ++i) {
    int g = i * 256 + tid;
    int m = g >> 2, f0 = (g & 3) * 4;
    *(float4*)&Ks[m][f0] = *(const float4*)&Kq[(size_t)(c * CHUNK + m) * (H * F) + h * F + f0];
  }
  #pragma unroll
  for (int i = 0; i < 4; ++i) {  // 1024 bf16x8 -> f32
    int g = i * 256 + tid;
    int m = g >> 3, e0 = (g & 7) * 8;
    bf16x8 vv = *(const bf16x8*)&Vb16[(size_t)(c * CHUNK + m) * 1024 + h * HD + e0];
    #pragma unroll
    for (int j = 0; j < 8; ++j) Vs[m][e0 + j] = bf2f(((const ushort*)&vv)[j]);
  }
  __syncthreads();
  const int f = tid >> 4, e0 = (tid & 15) * 4;
  float4 acc = make_float4(0.f, 0.f, 0.f, 0.f);
  for (int m = 0; m < CHUNK; ++m) {
    float kv = Ks[m][f];
    float4 v4 = *(const float4*)&Vs[m][e0];
    acc.x = fmaf(kv, v4.x, acc.x);
    acc.y = fmaf(kv, v4.y, acc.y);
    acc.z = fmaf(kv, v4.z, acc.z);
    acc.w = fmaf(kv, v4.w, acc.w);
  }
  *(float4*)&S[((((size_t)h * NC) + c) * F + f) * HD + e0] = acc;
  if (tid < F) {
    double s = 0.0;
    for (int m = 0; m < CHUNK; ++m) s += (double)Ks[m][tid];
    KS[(((size_t)h * NC) + c) * F + tid] = s;
  }
}

// ---------------------------------------------------------------------------
// Fused chunk attention v4  [proven round 10/11 body; V consumed as bf16].
// Grid (NC, H), 512 threads.
// ---------------------------------------------------------------------------
__global__ __launch_bounds__(512) void attn_chunk_v4(
    const float* __restrict__ Q, const float* __restrict__ Kq,
    const ushort* __restrict__ Vb16,
    const float* __restrict__ S, const double* __restrict__ KS,
    ushort* __restrict__ Yh) {
  const int c = blockIdx.x, h = blockIdx.y;
  __shared__ float Ks[CHUNK][F];
  __shared__ float Vs[CHUNK][HD];
  __shared__ float Ss[F][HD];
  __shared__ double kcs[F];
  __shared__ float zs[CHUNK];
  const int tid = threadIdx.x;

  {
    int m = tid >> 2, f0 = (tid & 3) * 4;
    *(float4*)&Ks[m][f0] = *(const float4*)&Kq[(size_t)(c * CHUNK + m) * (H * F) + h * F + f0];
  }
  #pragma unroll
  for (int i = 0; i < 2; ++i) {  // 1024 bf16x8 -> f32
    int g = i * 512 + tid;
    int m = g >> 3, e0 = (g & 7) * 8;
    bf16x8 vv = *(const bf16x8*)&Vb16[(size_t)(c * CHUNK + m) * 1024 + h * HD + e0];
    #pragma unroll
    for (int j = 0; j < 8; ++j) Vs[m][e0 + j] = bf2f(((const ushort*)&vv)[j]);
  }
  {
    float s0 = 0.f, s1 = 0.f;
    for (int cc = 0; cc < c; ++cc) {
      size_t base = (((size_t)h * NC) + cc) * (F * HD);
      s0 += S[base + tid];
      s1 += S[base + tid + 512];
    }
    ((float*)Ss)[tid] = s0;
    ((float*)Ss)[tid + 512] = s1;
  }
  if (tid < F) {
    double rk = 0.0;
    for (int cc = 0; cc < c; ++cc) rk += KS[(((size_t)h * NC) + cc) * F + tid];
    kcs[tid] = rk;
  }
  __syncthreads();

  const int w = tid >> 6;
  const int lane = tid & 63;
  const int rsub = lane >> 3;
  const int cg = lane & 7;
  const int e0 = cg * 8;
  const int lr = 8 * w + rsub;
  const int hr = 120 - 8 * w + rsub;

  float ql[F], qh[F];
  #pragma unroll
  for (int f0 = 0; f0 < F; f0 += 4) {
    *(float4*)&ql[f0] = *(const float4*)&Q[(size_t)(c * CHUNK + lr) * (H * F) + h * F + f0];
    *(float4*)&qh[f0] = *(const float4*)&Q[(size_t)(c * CHUNK + hr) * (H * F) + h * F + f0];
  }

  float accl[8], acch[8];
  #pragma unroll
  for (int j = 0; j < 8; ++j) { accl[j] = 0.f; acch[j] = 0.f; }
  float denl = 0.f, denh = 0.f;

  const int m1 = 8 * w + 8;
  const int m2 = 128 - 8 * w;
  for (int m = 0; m < m2; ++m) {
    float kr[F];
    #pragma unroll
    for (int f0 = 0; f0 < F; f0 += 4)
      *(float4*)&kr[f0] = *(const float4*)&Ks[m][f0];
    float v8[8];
    *(float4*)&v8[0] = *(const float4*)&Vs[m][e0];
    *(float4*)&v8[4] = *(const float4*)&Vs[m][e0 + 4];
    {
      float s = 0.f;
      #pragma unroll
      for (int f = 0; f < F; ++f) s = fmaf(qh[f], kr[f], s);
      float a = (m <= hr) ? s : 0.f;
      denh += a;
      #pragma unroll
      for (int j = 0; j < 8; ++j) acch[j] = fmaf(a, v8[j], acch[j]);
    }
    if (m < m1) {
      float s = 0.f;
      #pragma unroll
      for (int f = 0; f < F; ++f) s = fmaf(ql[f], kr[f], s);
      float a = (m <= lr) ? s : 0.f;
      denl += a;
      #pragma unroll
      for (int j = 0; j < 8; ++j) accl[j] = fmaf(a, v8[j], accl[j]);
    }
  }

  #pragma unroll
  for (int f = 0; f < F; ++f) {
    float s8[8];
    *(float4*)&s8[0] = *(const float4*)&Ss[f][e0];
    *(float4*)&s8[4] = *(const float4*)&Ss[f][e0 + 4];
    #pragma unroll
    for (int j = 0; j < 8; ++j) {
      accl[j] = fmaf(ql[f], s8[j], accl[j]);
      acch[j] = fmaf(qh[f], s8[j], acch[j]);
    }
  }

  if (cg == 0) {
    double dl = (double)denl, dh = (double)denh;
    #pragma unroll
    for (int f = 0; f < F; ++f) {
      dl += (double)ql[f] * kcs[f];
      dh += (double)qh[f] * kcs[f];
    }
    zs[lr] = (float)(1.0 / (dl + 1e-12));
    zs[hr] = (float)(1.0 / (dh + 1e-12));
  }
  __syncthreads();

  #pragma unroll
  for (int rr = 0; rr < 2; ++rr) {
    const int row = rr ? hr : lr;
    const float* ac = rr ? acch : accl;
    float zz = zs[row];
    ushort4 h4a, h4b;
    h4a.x = f2bf(ac[0] * zz); h4a.y = f2bf(ac[1] * zz);
    h4a.z = f2bf(ac[2] * zz); h4a.w = f2bf(ac[3] * zz);
    h4b.x = f2bf(ac[4] * zz); h4b.y = f2bf(ac[5] * zz);
    h4b.z = f2bf(ac[6] * zz); h4b.w = f2bf(ac[7] * zz);
    size_t base = (size_t)(c * CHUNK + row) * 1024 + h * HD + e0;
    *(ushort4*)&Yh[base]     = h4a;
    *(ushort4*)&Yh[base + 4] = h4b;
  }
}

// ---------------------------------------------------------------------------
// Plain bf16 single-product GEMM  [proven round 10] (Wo projection).
// ---------------------------------------------------------------------------
__global__ __launch_bounds__(256) void gemm_bf16_db(
    const ushort* __restrict__ A, const ushort* __restrict__ BT,
    float* __restrict__ C, int M, int N, int K) {
  constexpr int LDT = 40;
  __shared__ __bf16 As[2][64][LDT];
  __shared__ __bf16 Bs[2][64][LDT];
  const int tid  = threadIdx.x;
  const int wave = tid >> 6, lane = tid & 63;
  const int wr = (wave >> 1) * 32, wc = (wave & 1) * 32;
  const int nbx = gridDim.x, nwg = gridDim.x * gridDim.y;
  int bid = blockIdx.y * nbx + blockIdx.x;
  bid = (bid & 7) * (nwg >> 3) + (bid >> 3);
  const int brow = (bid / nbx) * 64, bcol = (bid % nbx) * 64;
  const int srow = tid >> 2, skg = (tid & 3) * 8;
  const size_t a_off = (size_t)(brow + srow) * K + skg;
  const size_t b_off = (size_t)(bcol + srow) * K + skg;

  f32x16 acc;
  #pragma unroll
  for (int i = 0; i < 16; ++i) acc[i] = 0.f;

  bf16x8 ra, rb;
  auto LOADT = [&](int k0) {
    ra = *(const bf16x8*)&A[a_off + k0];
    rb = *(const bf16x8*)&BT[b_off + k0];
  };
  auto WRITET = [&](int buf) {
    *(bf16x8*)&As[buf][srow][skg] = ra;
    *(bf16x8*)&Bs[buf][srow][skg] = rb;
  };

  const int NS = K / 32;
  LOADT(0); WRITET(0);
  __syncthreads();
  int cur = 0;
  for (int t = 0; t < NS; ++t) {
    if (t + 1 < NS) LOADT((t + 1) * 32);
    const int fr = lane & 31;
    const int kh = (lane >> 5) * 8;
    bf16x8 a0 = *(const bf16x8*)&As[cur][wr + fr][kh];
    bf16x8 a1 = *(const bf16x8*)&As[cur][wr + fr][16 + kh];
    bf16x8 b0 = *(const bf16x8*)&Bs[cur][wc + fr][kh];
    bf16x8 b1 = *(const bf16x8*)&Bs[cur][wc + fr][16 + kh];
    acc = __builtin_amdgcn_mfma_f32_32x32x16_bf16(a0, b0, acc, 0, 0, 0);
    acc = __builtin_amdgcn_mfma_f32_32x32x16_bf16(a1, b1, acc, 0, 0, 0);
    if (t + 1 < NS) WRITET(cur ^ 1);
    __syncthreads();
    cur ^= 1;
  }
  const int fr = lane & 31, fq = lane >> 5;
  #pragma unroll
  for (int r = 0; r < 16; ++r) {
    int row = brow + wr + (r & 3) + 8 * (r >> 2) + 4 * fq;
    C[(size_t)row * N + bcol + wc + fr] = acc[r];
  }
}

// ---------------------------------------------------------------------------
extern "C" void kernel_launch(void* const* d_in, const int* in_sizes, int n_in,
                              void* d_out, int out_size, void* d_ws, size_t ws_size,
                              hipStream_t stream) {
  const float* hs = (const float*)d_in[0];
  const float* Wq = (const float*)d_in[1];
  const float* Wk = (const float*)d_in[2];
  const float* Wv = (const float*)d_in[3];
  const float* Wo = (const float*)d_in[4];
  float* out = (float*)d_out;

  char* ws = (char*)d_ws;
  const size_t MB = 1 << 20;
  signed char* A8 = (signed char*)(ws + 0 * MB);   // 10 MB, dead after step 2
  signed char* W8 = (signed char*)(ws + 10 * MB);  // 2.5 MB, dead after step 2
  ushort* Ah   = (ushort*)(ws + 13 * MB);          // 4 MB, dead after step 2
  ushort* BvT  = (ushort*)(ws + 17 * MB);          // 2 MB
  ushort* BoT  = (ushort*)(ws + 19 * MB);          // 2 MB
  ushort* Vb16 = (ushort*)(ws + 21 * MB);          // 4 MB bf16
  float*  Qb   = (float*)(ws + 25 * MB);           // 2 MB  (peak 27 MB)
  float*  S    = (float*)(ws + 13 * MB);           // 1 MB, overlays dead Ah (step 3+)
  ushort* Ys   = (ushort*)(ws + 0 * MB);           // 4 MB bf16, overlays dead A8 (step 4+)
  // d_out as scratch (proven): fully overwritten by step 5.
  double* KS   = (double*)d_out;                   // 32 KB
  float*  Kb   = (float*)((char*)d_out + 1 * MB);  // 2 MB

  // 1) fused prep: Ah + A8 from hs; BvT, BoT, W8 from weights
  prep_all<<<dim3(5120), 256, 0, stream>>>(hs, Wv, Wo, Wq, Wk, Ah, A8, BvT, BoT, W8);
  // 2) fused independent GEMMs: exact QK (i8) + V projection (bf16 out)
  gemm_v_qk<<<dim3(512), 512, 0, stream>>>(A8, W8, Qb, Kb, Ah, BvT, Vb16);
  // 3) per-chunk k^T v states + fp64 k sums
  chunk_state<<<dim3(NC, H), 256, 0, stream>>>(Kb, Vb16, S, KS);
  // 4) fused chunk attention v4 -> Ys bf16
  attn_chunk_v4<<<dim3(NC, H), 512, 0, stream>>>(Qb, Kb, Vb16, S, KS, Ys);
  // 5) output projection (overwrites d_out, retiring KS/Kb scratch)
  gemm_bf16_db<<<dim3(16, 32), 256, 0, stream>>>(Ys, BoT, out, L, D, H * HD);
}